// Round 9
// baseline (515.153 us; speedup 1.0000x reference)
//
#include <hip/hip_runtime.h>
#include <hip/hip_bf16.h>

// Problem: T=255, B=256, NIN=784, NOUT=40
// out layout: [spk_rec (255*256*40) | mem_rec (255*256*40)] fp32
#define T_STEPS 255
#define BATCH 256
#define NIN 784
#define NOUT 40
#define MROWS (T_STEPS * BATCH)          // 65280
#define TBN (T_STEPS * BATCH * NOUT)     // 2611200
#define BN_CH (BATCH * NOUT)             // 10240

#define BM 128    // 4 rows/thread x 32 lane-rows -> grid 510
#define BK 56     // 784 = 14 * 56
#define LDX 60    // fp32 X LDS row stride (dwords)
#define LDWC 60   // fp32 W LDS row stride (dwords)

// fp64-VALU GEMM, 4 rows x 5 cols per thread, software-pipelined:
//  - next-quad LDS reads prefetched into registers before the FMA chain
//  - next-k0 global loads issued before the inner loop, ds_write after
//    the post-compute barrier (T14 async-stage split)
// FMA chain per output element is bit-identical to the validated round-2/8
// kernels (k ascending, quads of 4 sequential FMAs, fp64 cvt of fp32 data):
// cur is correctly-rounded fp32 -> spike decisions match the references.
__global__ __launch_bounds__(256) void lif_gemm_kernel(
    const float* __restrict__ X, const float* __restrict__ W,
    float* __restrict__ cur) {
  __shared__ float xs[BM * LDX];      // 30.0 KB
  __shared__ float wl[NOUT * LDWC];   // 9.6 KB
  const int tid = threadIdx.x;
  const int m0 = blockIdx.x * BM;
  const int w = tid >> 6;        // wave 0..3
  const int l = tid & 63;
  const int rl = l & 31;         // row within 32-row band
  const int h = l >> 5;          // col-half 0/1
  const int c0 = (w * 2 + h) * 5;  // col base: 8 groups of 5 -> 40 cols

  // staging coordinates (fixed per thread)
  const unsigned xr0 = tid / 14u, xc0 = tid % 14u;  // + i*256 pattern below

  double acc[4][5];
#pragma unroll
  for (int r = 0; r < 4; ++r)
#pragma unroll
    for (int c = 0; c < 5; ++c) acc[r][c] = 0.0;

  float4 gx[7], gw[3];
  (void)xr0; (void)xc0;

#define LOADG(K0)                                                         \
  do {                                                                    \
    _Pragma("unroll")                                                     \
    for (int i = 0; i < 7; ++i) {                                         \
      unsigned id = tid + i * 256u;                                       \
      unsigned row = id / 14u, c4 = id % 14u;                             \
      gx[i] = *reinterpret_cast<const float4*>(                           \
          X + (size_t)(m0 + row) * NIN + (K0) + c4 * 4);                  \
    }                                                                     \
    _Pragma("unroll")                                                     \
    for (int i = 0; i < 3; ++i) {                                         \
      unsigned id = tid + i * 256u;                                       \
      if (id < NOUT * 14u) {                                              \
        unsigned row = id / 14u, c4 = id % 14u;                           \
        gw[i] = *reinterpret_cast<const float4*>(                         \
            W + (size_t)row * NIN + (K0) + c4 * 4);                       \
      }                                                                   \
    }                                                                     \
  } while (0)

#define WRITEG()                                                          \
  do {                                                                    \
    _Pragma("unroll")                                                     \
    for (int i = 0; i < 7; ++i) {                                         \
      unsigned id = tid + i * 256u;                                       \
      unsigned row = id / 14u, c4 = id % 14u;                             \
      *reinterpret_cast<float4*>(&xs[row * LDX + c4 * 4]) = gx[i];        \
    }                                                                     \
    _Pragma("unroll")                                                     \
    for (int i = 0; i < 3; ++i) {                                         \
      unsigned id = tid + i * 256u;                                       \
      if (id < NOUT * 14u) {                                              \
        unsigned row = id / 14u, c4 = id % 14u;                           \
        *reinterpret_cast<float4*>(&wl[row * LDWC + c4 * 4]) = gw[i];     \
      }                                                                   \
    }                                                                     \
  } while (0)

  LOADG(0);
  WRITEG();
  __syncthreads();

  for (int k0 = 0; k0 < NIN; k0 += BK) {
    const bool has_next = (k0 + BK < NIN);
    if (has_next) LOADG(k0 + BK);  // issue early; waited on at WRITEG

    // register-prefetched inner loop over 14 quads
    float4 px[4], pw[5];
#pragma unroll
    for (int r = 0; r < 4; ++r)
      px[r] = *reinterpret_cast<const float4*>(&xs[(rl + 32 * r) * LDX]);
#pragma unroll
    for (int c = 0; c < 5; ++c)
      pw[c] = *reinterpret_cast<const float4*>(&wl[(c0 + c) * LDWC]);

#pragma unroll
    for (int kk = 0; kk < BK; kk += 4) {
      float4 cx[4], cw[5];
#pragma unroll
      for (int r = 0; r < 4; ++r) cx[r] = px[r];
#pragma unroll
      for (int c = 0; c < 5; ++c) cw[c] = pw[c];
      if (kk + 4 < BK) {  // prefetch next quad while FMAing this one
#pragma unroll
        for (int r = 0; r < 4; ++r)
          px[r] = *reinterpret_cast<const float4*>(
              &xs[(rl + 32 * r) * LDX + kk + 4]);
#pragma unroll
        for (int c = 0; c < 5; ++c)
          pw[c] = *reinterpret_cast<const float4*>(
              &wl[(c0 + c) * LDWC + kk + 4]);
      }
      double xd[4][4];
#pragma unroll
      for (int r = 0; r < 4; ++r) {
        xd[r][0] = (double)cx[r].x; xd[r][1] = (double)cx[r].y;
        xd[r][2] = (double)cx[r].z; xd[r][3] = (double)cx[r].w;
      }
#pragma unroll
      for (int c = 0; c < 5; ++c) {
        double wa = (double)cw[c].x, wb = (double)cw[c].y,
               wc = (double)cw[c].z, wd = (double)cw[c].w;
#pragma unroll
        for (int r = 0; r < 4; ++r) {
          acc[r][c] = fma(xd[r][0], wa, acc[r][c]);
          acc[r][c] = fma(xd[r][1], wb, acc[r][c]);
          acc[r][c] = fma(xd[r][2], wc, acc[r][c]);
          acc[r][c] = fma(xd[r][3], wd, acc[r][c]);
        }
      }
    }
    __syncthreads();
    if (has_next) {
      WRITEG();
      __syncthreads();
    }
  }

#pragma unroll
  for (int r = 0; r < 4; ++r) {
    const size_t mrow = (size_t)m0 + rl + 32 * r;
#pragma unroll
    for (int c = 0; c < 5; ++c)
      cur[mrow * NOUT + c0 + c] = (float)acc[r][c];
  }
#undef LOADG
#undef WRITEG
}

// One thread per (b, n) chain; 17 chunks of 15 t-steps, next chunk's cur
// loads prefetched before computing the current chunk (hides L2 latency).
// Per-step math identical to the validated scan (asm barrier blocks fma
// contraction of 0.95f*mem + cur, matching numpy's two roundings).
__global__ __launch_bounds__(64) void lif_scan_kernel(
    float* __restrict__ spk, float* __restrict__ curmem) {
  const int idx = blockIdx.x * 64 + threadIdx.x;  // 0..10239
  float mem = 0.f;
  float c[15];
#pragma unroll
  for (int i = 0; i < 15; ++i) c[i] = curmem[(size_t)i * BN_CH + idx];

  for (int ch = 0; ch < 17; ++ch) {
    const int t0 = ch * 15;
    float n[15];
    if (ch != 16) {
#pragma unroll
      for (int i = 0; i < 15; ++i)
        n[i] = curmem[(size_t)(t0 + 15 + i) * BN_CH + idx];
    }
    float m_[15], s_[15];
#pragma unroll
    for (int i = 0; i < 15; ++i) {
      float reset = (mem > 1.0f) ? 1.0f : 0.0f;
      float decay = 0.95f * mem;
      asm volatile("" : "+v"(decay));  // forbid fma contraction
      float summ = decay + c[i];
      float mnew = summ * (1.0f - reset);
      m_[i] = mnew;
      s_[i] = (mnew > 1.0f) ? 1.0f : 0.0f;
      mem = mnew;
    }
#pragma unroll
    for (int i = 0; i < 15; ++i) {
      curmem[(size_t)(t0 + i) * BN_CH + idx] = m_[i];
      spk[(size_t)(t0 + i) * BN_CH + idx] = s_[i];
    }
    if (ch != 16) {
#pragma unroll
      for (int i = 0; i < 15; ++i) c[i] = n[i];
    }
  }
}

extern "C" void kernel_launch(void* const* d_in, const int* in_sizes, int n_in,
                              void* d_out, int out_size, void* d_ws,
                              size_t ws_size, hipStream_t stream) {
  (void)in_sizes; (void)n_in; (void)out_size; (void)d_ws; (void)ws_size;
  const float* X = (const float*)d_in[0];
  const float* W = (const float*)d_in[1];
  float* out = (float*)d_out;
  float* spk = out;            // [255,256,40]
  float* memout = out + TBN;   // [255,256,40], used as cur scratch then mem

  lif_gemm_kernel<<<MROWS / BM, 256, 0, stream>>>(X, W, memout);
  lif_scan_kernel<<<BN_CH / 64, 64, 0, stream>>>(spk, memout);
}

// Round 10
// 146.782 us; speedup vs baseline: 3.5096x; 3.5096x over previous
//
#include <hip/hip_runtime.h>
#include <hip/hip_bf16.h>

// Problem: T=255, B=256, NIN=784, NOUT=40
// out layout: [spk_rec (255*256*40) | mem_rec (255*256*40)] fp32
#define T_STEPS 255
#define BATCH 256
#define NIN 784
#define NOUT 40
#define MROWS (T_STEPS * BATCH)          // 65280
#define TBN (T_STEPS * BATCH * NOUT)     // 2611200
#define BN_CH (BATCH * NOUT)             // 10240

#define BM 128    // 4 rows/thread x 32 lane-rows -> 510 tiles
#define BK 56     // 784 = 14*56; half-K 392 = 7*56
#define KSPLIT 392
#define LDX 60    // fp32 X LDS row stride (dwords)
#define LDWC 60   // fp32 W LDS row stride (dwords)

// Inner tile body shared by both GEMM variants: 4 rows x 5 cols per thread,
// FMA chain per output element bit-identical (within each K-range) to the
// validated round-2/8 kernels (k ascending, quads of 4 sequential FMAs,
// fp64 cvt of fp32 data).
template <typename AccT>
__device__ __forceinline__ void gemm_tiles(
    const float* __restrict__ X, const float* __restrict__ W,
    float* __restrict__ xs, float* __restrict__ wl,
    int m0, int kbeg, int kend, int tid, int rl, int c0,
    AccT acc[4][5]) {
  for (int k0 = kbeg; k0 < kend; k0 += BK) {
    // stage X tile: 128 rows x 56 cols fp32 = 1792 float4 / 256 thr = 7 each
#pragma unroll
    for (int i = 0; i < 7; ++i) {
      unsigned id = tid + i * 256u;
      unsigned row = id / 14u;  // 14 float4 per row
      unsigned c4 = id % 14u;
      float4 v = *reinterpret_cast<const float4*>(
          X + (size_t)(m0 + row) * NIN + k0 + c4 * 4);
      *reinterpret_cast<float4*>(&xs[row * LDX + c4 * 4]) = v;
    }
    // stage W tile: 40 rows x 56 cols fp32 = 560 float4
#pragma unroll
    for (int i = 0; i < 3; ++i) {
      unsigned id = tid + i * 256u;
      if (id < NOUT * 14u) {
        unsigned row = id / 14u;
        unsigned c4 = id % 14u;
        float4 v = *reinterpret_cast<const float4*>(
            W + (size_t)row * NIN + k0 + c4 * 4);
        *reinterpret_cast<float4*>(&wl[row * LDWC + c4 * 4]) = v;
      }
    }
    __syncthreads();

#pragma unroll
    for (int kk = 0; kk < BK; kk += 4) {
      double xd[4][4];
#pragma unroll
      for (int r = 0; r < 4; ++r) {
        float4 xv = *reinterpret_cast<const float4*>(
            &xs[(rl + 32 * r) * LDX + kk]);
        xd[r][0] = (double)xv.x; xd[r][1] = (double)xv.y;
        xd[r][2] = (double)xv.z; xd[r][3] = (double)xv.w;
      }
#pragma unroll
      for (int c = 0; c < 5; ++c) {
        float4 wv = *reinterpret_cast<const float4*>(
            &wl[(c0 + c) * LDWC + kk]);
        double wa = (double)wv.x, wb = (double)wv.y,
               wc = (double)wv.z, wd = (double)wv.w;
#pragma unroll
        for (int r = 0; r < 4; ++r) {
          acc[r][c] = fma(xd[r][0], wa, acc[r][c]);
          acc[r][c] = fma(xd[r][1], wb, acc[r][c]);
          acc[r][c] = fma(xd[r][2], wc, acc[r][c]);
          acc[r][c] = fma(xd[r][3], wd, acc[r][c]);
        }
      }
    }
    __syncthreads();
  }
}

// Split-K variant: grid (510, 2); each block sums its 392-k half in fp64 and
// writes fp64 partials to ws. 1020 blocks -> 4 blocks/CU -> 16 waves/CU so
// other waves' FMAs cover each wave's LDS-wait (R8 was 2 blocks/CU, where
// VALU-issue (80us) and LDS (70us) serialized to 155us).
__global__ __launch_bounds__(256) void lif_gemm_split(
    const float* __restrict__ X, const float* __restrict__ W,
    double* __restrict__ part) {
  __shared__ float xs[BM * LDX];      // 30.0 KB
  __shared__ float wl[NOUT * LDWC];   // 9.6 KB
  const int tid = threadIdx.x;
  const int m0 = blockIdx.x * BM;
  const int kh = blockIdx.y;          // 0/1 -> k in [kh*392, kh*392+392)
  const int w = tid >> 6;
  const int l = tid & 63;
  const int rl = l & 31;
  const int h = l >> 5;
  const int c0 = (w * 2 + h) * 5;

  double acc[4][5];
#pragma unroll
  for (int r = 0; r < 4; ++r)
#pragma unroll
    for (int c = 0; c < 5; ++c) acc[r][c] = 0.0;

  gemm_tiles(X, W, xs, wl, m0, kh * KSPLIT, (kh + 1) * KSPLIT,
             tid, rl, c0, acc);

  double* p = part + (size_t)kh * TBN;
#pragma unroll
  for (int r = 0; r < 4; ++r) {
    const size_t mrow = (size_t)m0 + rl + 32 * r;
#pragma unroll
    for (int c = 0; c < 5; ++c)
      p[mrow * NOUT + c0 + c] = acc[r][c];
  }
}

// cur = fp32(round(p0 + p1)); fp64 join keeps total error ~1e-13.
__global__ __launch_bounds__(256) void combine_kernel(
    const double* __restrict__ part, float* __restrict__ cur) {
  size_t i = (size_t)blockIdx.x * 256 + threadIdx.x;
  if (i < TBN) cur[i] = (float)(part[i] + part[TBN + i]);
}

// Fallback (exact round-8 kernel) if ws_size can't hold fp64 partials.
__global__ __launch_bounds__(256) void lif_gemm_full(
    const float* __restrict__ X, const float* __restrict__ W,
    float* __restrict__ cur) {
  __shared__ float xs[BM * LDX];
  __shared__ float wl[NOUT * LDWC];
  const int tid = threadIdx.x;
  const int m0 = blockIdx.x * BM;
  const int w = tid >> 6;
  const int l = tid & 63;
  const int rl = l & 31;
  const int h = l >> 5;
  const int c0 = (w * 2 + h) * 5;

  double acc[4][5];
#pragma unroll
  for (int r = 0; r < 4; ++r)
#pragma unroll
    for (int c = 0; c < 5; ++c) acc[r][c] = 0.0;

  gemm_tiles(X, W, xs, wl, m0, 0, NIN, tid, rl, c0, acc);

#pragma unroll
  for (int r = 0; r < 4; ++r) {
    const size_t mrow = (size_t)m0 + rl + 32 * r;
#pragma unroll
    for (int c = 0; c < 5; ++c)
      cur[mrow * NOUT + c0 + c] = (float)acc[r][c];
  }
}

// One thread per (b, n) chain; 17 chunks of 15 t-steps, next chunk's cur
// loads prefetched before computing the current chunk (hides L2 latency).
// Per-step math identical to the validated scan (asm barrier blocks fma
// contraction of 0.95f*mem + cur, matching numpy's two roundings).
__global__ __launch_bounds__(64) void lif_scan_kernel(
    float* __restrict__ spk, float* __restrict__ curmem) {
  const int idx = blockIdx.x * 64 + threadIdx.x;  // 0..10239
  float mem = 0.f;
  float c[15];
#pragma unroll
  for (int i = 0; i < 15; ++i) c[i] = curmem[(size_t)i * BN_CH + idx];

  for (int ch = 0; ch < 17; ++ch) {
    const int t0 = ch * 15;
    float n[15];
    if (ch != 16) {
#pragma unroll
      for (int i = 0; i < 15; ++i)
        n[i] = curmem[(size_t)(t0 + 15 + i) * BN_CH + idx];
    }
    float m_[15], s_[15];
#pragma unroll
    for (int i = 0; i < 15; ++i) {
      float reset = (mem > 1.0f) ? 1.0f : 0.0f;
      float decay = 0.95f * mem;
      asm volatile("" : "+v"(decay));  // forbid fma contraction
      float summ = decay + c[i];
      float mnew = summ * (1.0f - reset);
      m_[i] = mnew;
      s_[i] = (mnew > 1.0f) ? 1.0f : 0.0f;
      mem = mnew;
    }
#pragma unroll
    for (int i = 0; i < 15; ++i) {
      curmem[(size_t)(t0 + i) * BN_CH + idx] = m_[i];
      spk[(size_t)(t0 + i) * BN_CH + idx] = s_[i];
    }
    if (ch != 16) {
#pragma unroll
      for (int i = 0; i < 15; ++i) c[i] = n[i];
    }
  }
}

extern "C" void kernel_launch(void* const* d_in, const int* in_sizes, int n_in,
                              void* d_out, int out_size, void* d_ws,
                              size_t ws_size, hipStream_t stream) {
  (void)in_sizes; (void)n_in; (void)out_size;
  const float* X = (const float*)d_in[0];
  const float* W = (const float*)d_in[1];
  float* out = (float*)d_out;
  float* spk = out;            // [255,256,40]
  float* memout = out + TBN;   // [255,256,40], used as cur scratch then mem

  const size_t need = 2ull * TBN * sizeof(double);  // 41.8 MB fp64 partials
  if (ws_size >= need) {
    double* part = (double*)d_ws;
    dim3 grid(MROWS / BM, 2);
    lif_gemm_split<<<grid, 256, 0, stream>>>(X, W, part);
    combine_kernel<<<(TBN + 255) / 256, 256, 0, stream>>>(part, memout);
  } else {
    lif_gemm_full<<<MROWS / BM, 256, 0, stream>>>(X, W, memout);
  }
  lif_scan_kernel<<<BN_CH / 64, 64, 0, stream>>>(spk, memout);
}